// Round 7
// baseline (170.196 us; speedup 1.0000x reference)
//
#include <hip/hip_runtime.h>

#define LRELU_ALPHA 0.2f

typedef __bf16 bf16x8 __attribute__((ext_vector_type(8)));
typedef unsigned short u16;
typedef unsigned short u16x4v __attribute__((ext_vector_type(4)));
typedef unsigned short u16x8 __attribute__((ext_vector_type(8)));
typedef float f32x4 __attribute__((ext_vector_type(4)));
typedef int int4v __attribute__((ext_vector_type(4)));
typedef unsigned int u32;
typedef unsigned long long u64;

__device__ __forceinline__ u16 f2bf(float f) {
  unsigned int u = __float_as_uint(f);
  u += 0x7fffu + ((u >> 16) & 1u);   // RNE
  return (u16)(u >> 16);
}

// async global->LDS, 16B per active lane; dest = wave-uniform base + lane*16
__device__ __forceinline__ void gload16(const void* g, void* lds) {
  __builtin_amdgcn_global_load_lds(
      (const __attribute__((address_space(1))) void*)g,
      (__attribute__((address_space(3))) void*)lds, 16, 0, 0);
}

// ---------------- kernel 1: WbT[o][i] = bf16(W[i][o]) ----------------
__global__ __launch_bounds__(256) void wcast(const float* __restrict__ W,
                                             u16* __restrict__ WbT) {
  int idx = blockIdx.x * 256 + threadIdx.x;            // 65536
  WbT[idx] = f2bf(W[(idx & 255) * 256 + (idx >> 8)]);
}

// ---------------- kernel 2: pack adj -> 1-bit mask via ballot ---------
// grid 4096, block 256 / 4 waves; one row per wave, pure streaming.
__global__ __launch_bounds__(256) void packadj(const int* __restrict__ adj,
                                               u32* __restrict__ maskg) {
  const int tid = threadIdx.x;
  const int l = tid & 63, w = tid >> 6;
  const size_t row = (size_t)blockIdx.x * 4 + w;
  const int* arow = adj + row * 4096;
  u64* mrow = (u64*)(maskg + row * 128);
  for (int it = 0; it < 16; ++it) {
    const int* base = arow + it * 256;
    int v0 = base[l], v1 = base[l + 64], v2 = base[l + 128], v3 = base[l + 192];
    u64 b0 = __ballot(v0 != 0);
    u64 b1 = __ballot(v1 != 0);
    u64 b2 = __ballot(v2 != 0);
    u64 b3 = __ballot(v3 != 0);
    if (l == 0) {
      mrow[it * 4 + 0] = b0;
      mrow[it * 4 + 1] = b1;
      mrow[it * 4 + 2] = b2;
      mrow[it * 4 + 3] = b3;
    }
  }
}

// ---------------- kernel 3: Hh = bf16(h) @ W, fused s/d dots ----------
// Writes HhTt in DMA-friendly tiled layout:
// addr_u16(b,col,k) = b*1048576 + (k>>5)*8192 + (col>>4)*512
//                     + ((k>>3)&3)*128 + (col&15)*8 + (k&7)
__global__ __launch_bounds__(256) void gemm1(const float* __restrict__ h,
                                             const u16* __restrict__ WbT,
                                             const float* __restrict__ a,
                                             u16* __restrict__ HhTt,
                                             float* __restrict__ sbuf,
                                             float* __restrict__ dbuf) {
  const int tid = threadIdx.x, bid = blockIdx.x;
  const int l = tid & 63, w = tid >> 6;
  const int lr = l & 15;
  const int lk = (l >> 4) << 3;
  const int rowA = bid * 64 + 16 * w + lr;
  const float* hrow = h + (size_t)rowA * 256 + lk;

  f32x4 acc[16];
#pragma unroll
  for (int n = 0; n < 16; ++n) acc[n] = (f32x4){0.f, 0.f, 0.f, 0.f};

  for (int k0 = 0; k0 < 256; k0 += 32) {
    f32x4 a0 = *(const f32x4*)(hrow + k0);
    f32x4 a1 = *(const f32x4*)(hrow + k0 + 4);
    u16x8 au;
    au[0] = f2bf(a0[0]); au[1] = f2bf(a0[1]); au[2] = f2bf(a0[2]); au[3] = f2bf(a0[3]);
    au[4] = f2bf(a1[0]); au[5] = f2bf(a1[1]); au[6] = f2bf(a1[2]); au[7] = f2bf(a1[3]);
    bf16x8 af = __builtin_bit_cast(bf16x8, au);
#pragma unroll
    for (int n = 0; n < 16; ++n) {
      int4v bv = *(const int4v*)(WbT + (size_t)(16 * n + lr) * 256 + k0 + lk);
      bf16x8 bf = __builtin_bit_cast(bf16x8, bv);
      acc[n] = __builtin_amdgcn_mfma_f32_16x16x32_bf16(af, bf, acc[n], 0, 0, 0);
    }
  }

  float sp[4] = {0.f, 0.f, 0.f, 0.f}, dp[4] = {0.f, 0.f, 0.f, 0.f};
#pragma unroll
  for (int n = 0; n < 16; ++n) {
    int col = 16 * n + lr;
    float as = a[col];
    float ad = a[256 + col];
#pragma unroll
    for (int rr = 0; rr < 4; ++rr) {
      int row = bid * 64 + 16 * w + ((l >> 4) << 2) + rr;
      int bb = row >> 12, kk = row & 4095;
      float v = acc[n][rr];
      size_t addr = (size_t)bb * 1048576 + (size_t)(kk >> 5) * 8192 +
                    (col >> 4) * 512 + ((kk >> 3) & 3) * 128 + (col & 15) * 8 +
                    (kk & 7);
      HhTt[addr] = f2bf(v);
      sp[rr] += v * as;
      dp[rr] += v * ad;
    }
  }
#pragma unroll
  for (int rr = 0; rr < 4; ++rr) {
#pragma unroll
    for (int off = 1; off < 16; off <<= 1) {
      sp[rr] += __shfl_xor(sp[rr], off);
      dp[rr] += __shfl_xor(dp[rr], off);
    }
  }
  if ((l & 15) == 0) {
#pragma unroll
    for (int rr = 0; rr < 4; ++rr) {
      int row = bid * 64 + 16 * w + ((l >> 4) << 2) + rr;
      sbuf[row] = sp[rr];
      dbuf[row] = dp[rr];
    }
  }
}

// ---------------- kernel 4: main fused GAT aggregation ----------------
// grid 512 (2 blocks/CU!), 256 thr / 4 waves; 32 rows x 256 cols per block.
// All K-loop VMEM = counted DMA (4xB + 1xD per wave per step, vmcnt(5)).
// 3-buf Bt ring (B issued dist 2), Dt issued dist 3; e-gen 1 step ahead
// into double-buffered At; one raw barrier per step.
__global__ __launch_bounds__(256, 2) void gat_main(const u32* __restrict__ maskg,
                                                   const u16* __restrict__ HhTt,
                                                   const float* __restrict__ s,
                                                   const float* __restrict__ d,
                                                   float* __restrict__ out) {
  __shared__ __align__(16) u16 Bt[3][8192];    // 48 KB
  __shared__ __align__(16) u16 At[2][1024];    // 4 KB
  __shared__ __align__(16) u32 Mk[4096];       // 16 KB (rotated mask panel)
  __shared__ __align__(16) float Dt[3][32];    // 384 B
  __shared__ float rs_lds[32];

  const int tid = threadIdx.x, bid = blockIdx.x;
  const int xcd = bid & 7;
  const int t512 = (xcd << 6) | (bid >> 3);    // bijective; batch -> 2 XCDs
  const int b = t512 >> 7;
  const int rowbase = (t512 & 127) << 5;

  const int l = tid & 63, w = tid >> 6;
  const int lr = l & 15, lkg = l >> 4;
  const int er = tid >> 3, c8 = tid & 7;       // e-gen: row er, col-quad c8

  // ---- mask panel load (rotated so per-step reads are conflict-free) ----
  {
    const u32* mrow = maskg + ((size_t)(b * 4096 + rowbase)) * 128;
    const int r = tid >> 3;
    const int w0 = (tid & 7) * 16;
#pragma unroll
    for (int j = 0; j < 16; ++j) {
      int ww = w0 + j;
      Mk[r * 128 + ((ww + r) & 127)] = mrow[r * 128 + ww];
    }
  }

  const float s_e = s[b * 4096 + rowbase + er];

  // ---- DMA sources ----
  const char* bsrcB = (const char*)HhTt + (size_t)b * 2097152 + l * 16;
  const char* dsrcB = (const char*)d + (size_t)b * 16384 + w * 32 + l * 16;
  char* BtB = (char*)&Bt[0][0];
  char* DtB = (char*)&Dt[0][0];

  // ---- LDS read offsets (u16 units; R6-verified mapping) ----
  const int atoff0 = lr * 32 + lkg * 8;
  const int atoff1 = (16 + lr) * 32 + lkg * 8;
  const int btbase = (w * 4) * 512 + lkg * 128 + lr * 8;

  f32x4 acc0[4], acc1[4];
#pragma unroll
  for (int n = 0; n < 4; ++n) {
    acc0[n] = (f32x4){0.f, 0.f, 0.f, 0.f};
    acc1[n] = (f32x4){0.f, 0.f, 0.f, 0.f};
  }
  float racc = 0.f;

#define ISSUE_B(BUF, STEP)                                                    \
  {                                                                           \
    const size_t so_ = (size_t)(STEP) * 16384;                                \
    gload16(bsrcB + so_ + (w * 4 + 0) * 1024,                                 \
            BtB + (BUF) * 16384 + (w * 4 + 0) * 1024);                        \
    gload16(bsrcB + so_ + (w * 4 + 1) * 1024,                                 \
            BtB + (BUF) * 16384 + (w * 4 + 1) * 1024);                        \
    gload16(bsrcB + so_ + (w * 4 + 2) * 1024,                                 \
            BtB + (BUF) * 16384 + (w * 4 + 2) * 1024);                        \
    gload16(bsrcB + so_ + (w * 4 + 3) * 1024,                                 \
            BtB + (BUF) * 16384 + (w * 4 + 3) * 1024);                        \
  }

#define ISSUE_D(STEP)                                                         \
  {                                                                           \
    const int dst_ = (STEP) > 127 ? 127 : (STEP);                             \
    if (l < 2) gload16(dsrcB + (size_t)dst_ * 128,                            \
                       DtB + (dst_ % 3) * 128 + w * 32 + l * 16);             \
  }

#define EGEN(BA, STEP)                                                        \
  {                                                                           \
    u32 mword = Mk[er * 128 + (((STEP) + er) & 127)];                         \
    u32 m4 = mword >> (c8 * 4);                                               \
    f32x4 dv = *(const f32x4*)(DtB + ((STEP) % 3) * 128 + c8 * 16);           \
    u16x4v ev;                                                                \
    _Pragma("unroll")                                                         \
    for (int j = 0; j < 4; ++j) {                                             \
      float lg = s_e + dv[j];                                                 \
      float t = fmaxf(lg, LRELU_ALPHA * lg);                                  \
      float e = ((m4 >> j) & 1) ? __expf(-t) : 0.f;                           \
      racc += e;                                                              \
      ev[j] = f2bf(e);                                                        \
    }                                                                         \
    *(u16x4v*)&At[BA][er * 32 + c8 * 4] = ev;                                 \
  }

#define COMPUTE(BB, BA)                                                       \
  {                                                                           \
    bf16x8 af0 = __builtin_bit_cast(bf16x8, *(const int4v*)&At[BA][atoff0]);  \
    bf16x8 af1 = __builtin_bit_cast(bf16x8, *(const int4v*)&At[BA][atoff1]);  \
    __builtin_amdgcn_s_setprio(1);                                            \
    _Pragma("unroll")                                                         \
    for (int n = 0; n < 4; ++n) {                                             \
      bf16x8 bfv = __builtin_bit_cast(bf16x8,                                 \
          *(const int4v*)&Bt[BB][btbase + n * 512]);                          \
      acc0[n] = __builtin_amdgcn_mfma_f32_16x16x32_bf16(af0, bfv, acc0[n],    \
                                                        0, 0, 0);             \
      acc1[n] = __builtin_amdgcn_mfma_f32_16x16x32_bf16(af1, bfv, acc1[n],    \
                                                        0, 0, 0);             \
    }                                                                         \
    __builtin_amdgcn_s_setprio(0);                                            \
  }

// step J: issue B(J+2), D(J+3); e-gen step J+1 (reads Dt[(J+1)%3], published
// end of J-1); compute (Bt[J%3], At[J&1]); then lgkm(0) + vmcnt(5) + barrier.
// vmcnt(5) completes B(J+1)x4 and D(J+2), leaving exactly [B(J+2)x4, D(J+3)].
#define SUBSTEP(J, BB, BA, BI, BAN)                                           \
  {                                                                           \
    ISSUE_B(BI, (J) + 2)                                                      \
    ISSUE_D((J) + 3)                                                          \
    EGEN(BAN, (J) + 1)                                                        \
    COMPUTE(BB, BA)                                                           \
    asm volatile("s_waitcnt lgkmcnt(0)" ::: "memory");                        \
    asm volatile("s_waitcnt vmcnt(5)" ::: "memory");                          \
    __builtin_amdgcn_s_barrier();                                             \
  }

  // ---- prologue: B(0),B(1), D(1),D(2) staged; EGEN(0) from registers ----
  ISSUE_B(0, 0)
  ISSUE_B(1, 1)
  ISSUE_D(1)
  ISSUE_D(2)
  f32x4 d0v = *(const f32x4*)(d + b * 4096 + c8 * 4);   // d for step 0
  __syncthreads();   // Mk/s visible; drains all DMAs (once, prologue only)
  {
    u32 mword = Mk[er * 128 + (er & 127)];
    u32 m4 = mword >> (c8 * 4);
    u16x4v ev;
#pragma unroll
    for (int j = 0; j < 4; ++j) {
      float lg = s_e + d0v[j];
      float t = fmaxf(lg, LRELU_ALPHA * lg);
      float e = ((m4 >> j) & 1) ? __expf(-t) : 0.f;
      racc += e;
      ev[j] = f2bf(e);
    }
    *(u16x4v*)&At[0][er * 32 + c8 * 4] = ev;
  }
  asm volatile("s_waitcnt lgkmcnt(0)" ::: "memory");
  __builtin_amdgcn_s_barrier();

  for (int k = 0; k < 126; k += 6) {
    SUBSTEP(k + 0, 0, 0, 2, 1)
    SUBSTEP(k + 1, 1, 1, 0, 0)
    SUBSTEP(k + 2, 2, 0, 1, 1)
    SUBSTEP(k + 3, 0, 1, 2, 0)
    SUBSTEP(k + 4, 1, 0, 0, 1)
    SUBSTEP(k + 5, 2, 1, 1, 0)
  }
  // tail: J=126 (no issues), J=127
  EGEN(1, 127)
  COMPUTE(0, 0)
  asm volatile("s_waitcnt lgkmcnt(0)" ::: "memory");
  asm volatile("s_waitcnt vmcnt(0)" ::: "memory");
  __builtin_amdgcn_s_barrier();
  COMPUTE(1, 1)
#undef ISSUE_B
#undef ISSUE_D
#undef EGEN
#undef COMPUTE
#undef SUBSTEP

  // ---- rowsum: reduce the 8 c8-partials of each row ----
  racc += __shfl_xor(racc, 1);
  racc += __shfl_xor(racc, 2);
  racc += __shfl_xor(racc, 4);
  if (c8 == 0) rs_lds[er] = (racc == 0.f) ? 1.f : racc;
  __syncthreads();

  // ---- epilogue: divide + elu + store ----
#pragma unroll
  for (int t16 = 0; t16 < 2; ++t16) {
#pragma unroll
    for (int n = 0; n < 4; ++n) {
#pragma unroll
      for (int reg = 0; reg < 4; ++reg) {
        int rloc = 16 * t16 + lkg * 4 + reg;
        int col = w * 64 + 16 * n + lr;
        float v = (t16 ? acc1[n][reg] : acc0[n][reg]) / rs_lds[rloc];
        out[((size_t)(b * 4096 + rowbase + rloc)) * 256 + col] =
            v > 0.f ? v : (__expf(v) - 1.f);
      }
    }
  }
}

extern "C" void kernel_launch(void* const* d_in, const int* in_sizes, int n_in,
                              void* d_out, int out_size, void* d_ws, size_t ws_size,
                              hipStream_t stream) {
  const float* h = (const float*)d_in[0];
  const int* adj = (const int*)d_in[1];
  const float* W = (const float*)d_in[2];
  const float* a = (const float*)d_in[3];
  float* out = (float*)d_out;

  u16* WbT   = (u16*)d_ws;                                       // 128 KB
  u16* HhTt  = (u16*)((char*)d_ws + 131072);                     // 8 MB
  float* sb  = (float*)((char*)d_ws + 131072 + 8388608);         // 64 KB
  float* db  = sb + 16384;                                       // 64 KB
  u32* maskg = (u32*)((char*)d_ws + 131072 + 8388608 + 131072);  // 8 MB

  hipLaunchKernelGGL(wcast,    dim3(256),  dim3(256), 0, stream, W, WbT);
  hipLaunchKernelGGL(packadj,  dim3(4096), dim3(256), 0, stream, adj, maskg);
  hipLaunchKernelGGL(gemm1,    dim3(256),  dim3(256), 0, stream, h, WbT, a, HhTt, sb, db);
  hipLaunchKernelGGL(gat_main, dim3(512),  dim3(256), 0, stream, maskg, HhTt, sb, db, out);
}